// Round 3
// baseline (179.965 us; speedup 1.0000x reference)
//
#include <hip/hip_runtime.h>
#include <hip/hip_bf16.h>

// Problem constants: N=B*T=65536, D=256, K=1024
#define NTOT 65536
#define DDIM 256
#define KCB  1024
#define ND   16777216   // NTOT * DDIM

typedef __attribute__((ext_vector_type(8))) short bf16x8;   // 8 bf16 = 4 VGPRs
typedef __attribute__((ext_vector_type(4))) float f32x4;

__device__ static inline short f2bf(float f) {
    union { __hip_bfloat16 h; short s; } u;
    u.h = __float2bfloat16(f);   // RNE
    return u.s;
}

// ---------------- Prep: codebook fp32->bf16 fragments + 0.5||e||^2 + zero loss
// 32768 threads; thread -> (code c = gid>>5, j = gid&31, d = j*8). Reads fully
// coalesced. Fragment slot s = (chunk*8+ks)*64 + l with chunk=c>>4, ks=d>>5,
// l=((d>>3)&3)*16 + (c&15): B-frag for 16x16x32 is then 16B/lane at
// cbf + ((chunk*8+ks)*64 + lane)*8 shorts -> one coalesced dwordx4 per frag.
__global__ __launch_bounds__(256) void vq_prep_kernel(const float* __restrict__ cb,
                                                      short* __restrict__ cbf,
                                                      float* __restrict__ half_esq,
                                                      float* __restrict__ loss_out) {
    int gid = blockIdx.x * 256 + threadIdx.x;   // 0..32767
    int c = gid >> 5;
    int j = gid & 31;
    const float* p = cb + (size_t)c * DDIM + j * 8;
    f32x4 x = *(const f32x4*)p;
    f32x4 y = *(const f32x4*)(p + 4);
    float ss = x[0]*x[0] + x[1]*x[1] + x[2]*x[2] + x[3]*x[3]
             + y[0]*y[0] + y[1]*y[1] + y[2]*y[2] + y[3]*y[3];
    #pragma unroll
    for (int m = 16; m; m >>= 1) ss += __shfl_xor(ss, m);   // reduce over the 32 lanes of code c
    if (j == 0) half_esq[c] = 0.5f * ss;
    bf16x8 o;
    o[0] = f2bf(x[0]); o[1] = f2bf(x[1]); o[2] = f2bf(x[2]); o[3] = f2bf(x[3]);
    o[4] = f2bf(y[0]); o[5] = f2bf(y[1]); o[6] = f2bf(y[2]); o[7] = f2bf(y[3]);
    int s = ((c >> 4) * 8 + (j >> 2)) * 64 + (j & 3) * 16 + (c & 15);
    *(bf16x8*)(cbf + (size_t)s * 8) = o;
    if (gid == 0) loss_out[0] = 0.f;
}

// ---------------- Main: barrier-free bf16-MFMA K-loop + argmin + gather ------
// 1024 blocks x 256 thr (4 waves). Block owns 64 z-rows; wave w owns cols
// [w*256, w*256+256) as 16 chunks of 16. A (64 rows x 256 d) lives in regs
// (rf=4); B frags stream global->VGPR (L2-hot), software-pipelined half-chunks.
// Loss computed analytically: ||z-e*||^2 = ||z||^2 - 2*bestscore.
__global__ __launch_bounds__(256, 2) void vq_main_kernel(const float* __restrict__ z,
                                                         const float* __restrict__ cb,
                                                         const short* __restrict__ cbf,
                                                         const float* __restrict__ half_esq,
                                                         float* __restrict__ out) {
    __shared__ float esq_s[KCB];        // 4 KB
    __shared__ float zsq_s[64];
    __shared__ float bv_s[64 * 65];     // stride 65 breaks bank aliasing in reduce
    __shared__ int   bk_s[64 * 65];
    __shared__ float pv_s[256];
    __shared__ int   pk_s[256];
    __shared__ int   idx_s[64];

    const int tid  = threadIdx.x;
    const int w    = tid >> 6;
    const int lane = tid & 63;
    const int q    = lane >> 4;
    const int ln   = lane & 15;
    const int b0   = blockIdx.x * 64;

    #pragma unroll
    for (int i = 0; i < 4; ++i) esq_s[tid + i * 256] = half_esq[tid + i * 256];

    // ---- A fragments (all 64 rows, rf=4) + exact fp32 ||z_row||^2 ----------
    // A layout per 16x16x32 mfma: m = lane&15, k = (lane>>4)*8 + j.
    bf16x8 a[4][8];
    float zsq[4];
    #pragma unroll
    for (int rf = 0; rf < 4; ++rf) {
        zsq[rf] = 0.f;
        const float* ap0 = z + (size_t)(b0 + rf * 16 + ln) * DDIM + q * 8;
        #pragma unroll
        for (int ks = 0; ks < 8; ++ks) {
            f32x4 x = *(const f32x4*)(ap0 + ks * 32);
            f32x4 y = *(const f32x4*)(ap0 + ks * 32 + 4);
            zsq[rf] += x[0]*x[0] + x[1]*x[1] + x[2]*x[2] + x[3]*x[3]
                     + y[0]*y[0] + y[1]*y[1] + y[2]*y[2] + y[3]*y[3];
            bf16x8 t;
            t[0] = f2bf(x[0]); t[1] = f2bf(x[1]); t[2] = f2bf(x[2]); t[3] = f2bf(x[3]);
            t[4] = f2bf(y[0]); t[5] = f2bf(y[1]); t[6] = f2bf(y[2]); t[7] = f2bf(y[3]);
            a[rf][ks] = t;
        }
        // sum the 4 q-quarters of each row (lanes ln, ln+16, ln+32, ln+48)
        zsq[rf] += __shfl_xor(zsq[rf], 16);
        zsq[rf] += __shfl_xor(zsq[rf], 32);
    }
    if (w == 0 && q == 0) {
        #pragma unroll
        for (int rf = 0; rf < 4; ++rf) zsq_s[rf * 16 + ln] = zsq[rf];
    }
    __syncthreads();   // esq_s + zsq_s ready (the ONLY pre-reduce barrier)

    // ---- K-loop: wave-private cols, B direct global->VGPR, no barriers -----
    float bestv[16];
    int   bestk[16];
    #pragma unroll
    for (int i = 0; i < 16; ++i) { bestv[i] = -1e30f; bestk[i] = 0; }

    const short* bwave = cbf + (size_t)w * 65536;   // wave's 16 chunks * 8 ks * 64 lanes * 8 shorts

    bf16x8 B0[4], B1[4];
    #pragma unroll
    for (int t = 0; t < 4; ++t)
        B0[t] = *(const bf16x8*)(bwave + (((size_t)(0 * 8 + t) * 64 + lane) << 3));

    for (int c = 0; c < 16; ++c) {
        f32x4 acc[4];
        #pragma unroll
        for (int rf = 0; rf < 4; ++rf) acc[rf] = (f32x4){0.f, 0.f, 0.f, 0.f};

        // prefetch second half of this chunk
        #pragma unroll
        for (int t = 0; t < 4; ++t)
            B1[t] = *(const bf16x8*)(bwave + (((size_t)(c * 8 + 4 + t) * 64 + lane) << 3));
        #pragma unroll
        for (int t = 0; t < 4; ++t) {
            #pragma unroll
            for (int rf = 0; rf < 4; ++rf)
                acc[rf] = __builtin_amdgcn_mfma_f32_16x16x32_bf16(a[rf][t], B0[t], acc[rf], 0, 0, 0);
        }
        // prefetch first half of next chunk (wraps to chunk 0 on last iter - harmless)
        const int cn = (c + 1) & 15;
        #pragma unroll
        for (int t = 0; t < 4; ++t)
            B0[t] = *(const bf16x8*)(bwave + (((size_t)(cn * 8 + t) * 64 + lane) << 3));
        #pragma unroll
        for (int t = 0; t < 4; ++t) {
            #pragma unroll
            for (int rf = 0; rf < 4; ++rf)
                acc[rf] = __builtin_amdgcn_mfma_f32_16x16x32_bf16(a[rf][4 + t], B1[t], acc[rf], 0, 0, 0);
        }

        // score = cross - 0.5||e||^2. C/D: col=lane&15, row=q*4+i (verified).
        // k ascends over c per lane -> strict '>' keeps lowest index.
        const int col = w * 256 + c * 16 + ln;
        const float e = esq_s[col];
        #pragma unroll
        for (int rf = 0; rf < 4; ++rf) {
            #pragma unroll
            for (int i = 0; i < 4; ++i) {
                float s = acc[rf][i] - e;
                int sl = rf * 4 + i;
                if (s > bestv[sl]) { bestv[sl] = s; bestk[sl] = col; }
            }
        }
    }

    // ---- block argmin reduce: 64 candidates per row (4 waves x 16 lanes) ---
    #pragma unroll
    for (int rf = 0; rf < 4; ++rf) {
        #pragma unroll
        for (int i = 0; i < 4; ++i) {
            int row = rf * 16 + q * 4 + i;
            bv_s[row * 65 + w * 16 + ln] = bestv[rf * 4 + i];
            bk_s[row * 65 + w * 16 + ln] = bestk[rf * 4 + i];
        }
    }
    __syncthreads();
    {
        int row = tid & 63, part = tid >> 6;
        const float* pv = bv_s + row * 65 + part * 16;
        const int*   pk = bk_s + row * 65 + part * 16;
        float bv = pv[0]; int bk = pk[0];
        #pragma unroll
        for (int t = 1; t < 16; ++t) {
            float v = pv[t]; int kk = pk[t];
            if (v > bv || (v == bv && kk < bk)) { bv = v; bk = kk; }
        }
        pv_s[part * 64 + row] = bv;
        pk_s[part * 64 + row] = bk;
    }
    __syncthreads();
    if (tid < 64) {
        float bv = pv_s[tid]; int bk = pk_s[tid];
        #pragma unroll
        for (int p = 1; p < 4; ++p) {   // parts ascend in col order -> ties keep lowest k
            float v = pv_s[p * 64 + tid]; int kk = pk_s[p * 64 + tid];
            if (v > bv || (v == bv && kk < bk)) { bv = v; bk = kk; }
        }
        idx_s[tid] = bk;
        float lsum = zsq_s[tid] - 2.f * bv;   // ||z-e*||^2 for this row
        #pragma unroll
        for (int off = 32; off; off >>= 1) lsum += __shfl_down(lsum, off);
        if (tid == 0) atomicAdd(out + ND, lsum * (1.0f / (float)ND));
    }
    __syncthreads();

    // ---- epilogue: pure float4 gather + store (no z re-read) ---------------
    #pragma unroll
    for (int i = 0; i < 16; ++i) {
        int item = tid + i * 256;
        int row = item >> 6, c4 = item & 63;
        int k = idx_s[row];
        f32x4 v = *(const f32x4*)(cb + (size_t)k * DDIM + c4 * 4);
        *(f32x4*)(out + (size_t)(b0 + row) * DDIM + c4 * 4) = v;
    }
}

extern "C" void kernel_launch(void* const* d_in, const int* in_sizes, int n_in,
                              void* d_out, int out_size, void* d_ws, size_t ws_size,
                              hipStream_t stream) {
    const float* z  = (const float*)d_in[0];   // z_e, 65536 x 256 fp32
    const float* cb = (const float*)d_in[1];   // codebook, 1024 x 256 fp32
    float* out = (float*)d_out;                // z_q (16777216) ++ loss (1)

    float* half_esq = (float*)d_ws;                         // 4 KB
    short* cb_frag  = (short*)((char*)d_ws + 4096);         // 512 KB bf16 fragments

    vq_prep_kernel<<<128, 256, 0, stream>>>(cb, cb_frag, half_esq, out + ND);
    vq_main_kernel<<<NTOT / 64, 256, 0, stream>>>(z, cb, cb_frag, half_esq, out);
}

// Round 4
// 157.408 us; speedup vs baseline: 1.1433x; 1.1433x over previous
//
#include <hip/hip_runtime.h>
#include <hip/hip_bf16.h>

// Problem constants: N=B*T=65536, D=256, K=1024
#define NTOT 65536
#define DDIM 256
#define KCB  1024
#define ND   16777216   // NTOT * DDIM

typedef __attribute__((ext_vector_type(8))) short bf16x8;   // 8 bf16 = 4 VGPRs
typedef __attribute__((ext_vector_type(4))) float f32x4;

__device__ static inline short f2bf(float f) {
    union { __hip_bfloat16 h; short s; } u;
    u.h = __float2bfloat16(f);   // RNE
    return u.s;
}

// ---------------- Prep: codebook fp32->bf16 fragments + 0.5||e||^2 + zero loss
// Thread -> (code c = gid>>5, j = gid&31, d = j*8); fully coalesced reads.
// Fragment slot s = ((r*4 + cf)*8 + ks)*64 + l  with r=c>>6, cf=(c>>4)&3,
// ks=j>>2, l=(j&3)*16 + (c&15). Round r's 64 cols occupy one contiguous
// 32 KB span -> staging is a pure linear copy; B-frag (cf,ks) is 16B/lane at
// offset ((cf*8+ks)*64+lane)*16 inside the buffer (conflict-free ds_read_b128).
__global__ __launch_bounds__(256) void vq_prep_kernel(const float* __restrict__ cb,
                                                      short* __restrict__ cbf,
                                                      float* __restrict__ half_esq,
                                                      float* __restrict__ loss_out) {
    int gid = blockIdx.x * 256 + threadIdx.x;   // 0..32767
    int c = gid >> 5;
    int j = gid & 31;
    const float* p = cb + (size_t)c * DDIM + j * 8;
    f32x4 x = *(const f32x4*)p;
    f32x4 y = *(const f32x4*)(p + 4);
    float ss = x[0]*x[0] + x[1]*x[1] + x[2]*x[2] + x[3]*x[3]
             + y[0]*y[0] + y[1]*y[1] + y[2]*y[2] + y[3]*y[3];
    #pragma unroll
    for (int m = 16; m; m >>= 1) ss += __shfl_xor(ss, m);   // reduce 32 lanes of code c
    if (j == 0) half_esq[c] = 0.5f * ss;
    bf16x8 o;
    o[0] = f2bf(x[0]); o[1] = f2bf(x[1]); o[2] = f2bf(x[2]); o[3] = f2bf(x[3]);
    o[4] = f2bf(y[0]); o[5] = f2bf(y[1]); o[6] = f2bf(y[2]); o[7] = f2bf(y[3]);
    int s = (((c >> 6) * 4 + ((c >> 4) & 3)) * 8 + (j >> 2)) * 64 + (j & 3) * 16 + (c & 15);
    *(bf16x8*)(cbf + (size_t)s * 8) = o;
    if (gid == 0) loss_out[0] = 0.f;
}

// ---------------- Main: double-buffered staged bf16-MFMA + argmin + gather ---
// 1024 blocks x 256 thr (4 waves = 2 row-groups x 2 col-groups).
// Block: 64 rows x 1024 cols. A (32 rows/wave) in regs: a[2][8] = 64 VGPRs.
// 16 rounds x 64 cols; stage round r+1 (32 KB via global_load_lds w=16) while
// computing round r; ONE barrier per round (its vmcnt drain lands after the
// compute phase -> staging latency hidden).
__global__ __launch_bounds__(256, 2) void vq_main_kernel(const float* __restrict__ z,
                                                         const float* __restrict__ cb,
                                                         const short* __restrict__ cbf,
                                                         const float* __restrict__ half_esq,
                                                         float* __restrict__ out) {
    __shared__ short Bs[2][16384];   // 2 x 32 KB staging buffers
    __shared__ float esq_s[KCB];     // 4 KB
    __shared__ float zsq_s[64];
    __shared__ int   idx_s[64];

    const int tid  = threadIdx.x;
    const int w    = tid >> 6;
    const int lane = tid & 63;
    const int rg   = w >> 1;        // row-group: rows rg*32..rg*32+31
    const int cg   = w & 1;         // col-group: 32 of the round's 64 cols
    const int q    = lane >> 4;
    const int ln   = lane & 15;
    const int b0   = blockIdx.x * 64;

    // ---- issue round-0 staging FIRST: A-phase (~2k cyc) hides its latency --
    {
        const char* gsrc = (const char*)cbf + (size_t)w * 8192 + lane * 16;
        char*       ldst = (char*)&Bs[0][0] + w * 8192;   // wave-uniform; HW adds lane*16
        #pragma unroll
        for (int i = 0; i < 8; ++i)
            __builtin_amdgcn_global_load_lds(
                (const __attribute__((address_space(1))) unsigned int*)(gsrc + i * 1024),
                (__attribute__((address_space(3))) unsigned int*)(ldst + i * 1024),
                16, 0, 0);
    }

    #pragma unroll
    for (int i = 0; i < 4; ++i) esq_s[tid + i * 256] = half_esq[tid + i * 256];

    // ---- A fragments (32 rows/wave) + exact fp32 ||z_row||^2 ---------------
    // A layout: m = lane&15, k = (lane>>4)*8 + j.
    bf16x8 a[2][8];
    #pragma unroll
    for (int rf = 0; rf < 2; ++rf) {
        float zq = 0.f;
        const float* ap0 = z + (size_t)(b0 + rg * 32 + rf * 16 + ln) * DDIM + q * 8;
        #pragma unroll
        for (int ks = 0; ks < 8; ++ks) {
            f32x4 x = *(const f32x4*)(ap0 + ks * 32);
            f32x4 y = *(const f32x4*)(ap0 + ks * 32 + 4);
            zq += x[0]*x[0] + x[1]*x[1] + x[2]*x[2] + x[3]*x[3]
                + y[0]*y[0] + y[1]*y[1] + y[2]*y[2] + y[3]*y[3];
            bf16x8 t;
            t[0] = f2bf(x[0]); t[1] = f2bf(x[1]); t[2] = f2bf(x[2]); t[3] = f2bf(x[3]);
            t[4] = f2bf(y[0]); t[5] = f2bf(y[1]); t[6] = f2bf(y[2]); t[7] = f2bf(y[3]);
            a[rf][ks] = t;
        }
        zq += __shfl_xor(zq, 16);
        zq += __shfl_xor(zq, 32);          // full-row sum in every lane
        if (cg == 0 && q == 0) zsq_s[rg * 32 + rf * 16 + ln] = zq;
    }
    __syncthreads();   // esq_s, zsq_s ready; round-0 staging drained (vmcnt0)

    // ---- K-loop: 16 rounds, double-buffered -------------------------------
    float bestv[8];
    int   bestk[8];
    #pragma unroll
    for (int i = 0; i < 8; ++i) { bestv[i] = -1e30f; bestk[i] = 0; }

    #pragma unroll 2
    for (int r = 0; r < 16; ++r) {
        const int cur = r & 1;
        if (r < 15) {   // prefetch round r+1 into the other buffer
            const char* gsrc = (const char*)cbf + (size_t)(r + 1) * 32768 + w * 8192 + lane * 16;
            char*       ldst = (char*)&Bs[cur ^ 1][0] + w * 8192;
            #pragma unroll
            for (int i = 0; i < 8; ++i)
                __builtin_amdgcn_global_load_lds(
                    (const __attribute__((address_space(1))) unsigned int*)(gsrc + i * 1024),
                    (__attribute__((address_space(3))) unsigned int*)(ldst + i * 1024),
                    16, 0, 0);
        }

        f32x4 acc[2][2];
        #pragma unroll
        for (int rf = 0; rf < 2; ++rf)
            #pragma unroll
            for (int cl = 0; cl < 2; ++cl)
                acc[rf][cl] = (f32x4){0.f, 0.f, 0.f, 0.f};

        const short* bb = &Bs[cur][0] + ((size_t)cg * 16 * 64 + lane) * 8;  // cf = cg*2 + cl
        #pragma unroll
        for (int ks = 0; ks < 8; ++ks) {
            #pragma unroll
            for (int cl = 0; cl < 2; ++cl) {
                bf16x8 b = *(const bf16x8*)(bb + ((size_t)cl * 8 + ks) * 64 * 8);
                acc[0][cl] = __builtin_amdgcn_mfma_f32_16x16x32_bf16(a[0][ks], b, acc[0][cl], 0, 0, 0);
                acc[1][cl] = __builtin_amdgcn_mfma_f32_16x16x32_bf16(a[1][ks], b, acc[1][cl], 0, 0, 0);
            }
        }

        // score = cross - 0.5||e||^2 ; C/D: col=lane&15, row=q*4+i.
        // k ascends over (r, cl) per lane -> strict '>' keeps lowest index.
        #pragma unroll
        for (int cl = 0; cl < 2; ++cl) {
            const int col = r * 64 + (cg * 2 + cl) * 16 + ln;
            const float e = esq_s[col];
            #pragma unroll
            for (int rf = 0; rf < 2; ++rf)
                #pragma unroll
                for (int i = 0; i < 4; ++i) {
                    float s = acc[rf][cl][i] - e;
                    int sl = rf * 4 + i;
                    if (s > bestv[sl]) { bestv[sl] = s; bestk[sl] = col; }
                }
        }
        __syncthreads();   // cur fully read (safe to overwrite) + prefetch drained
    }

    // ---- block argmin reduce: 32 candidates per row (2 cg x 16 lanes) ------
    float* bv_s = (float*)&Bs[0][0];                 // 64 x 33 floats (stride 33: no bank clash)
    int*   bk_s = (int*)((char*)&Bs[0][0] + 16384);
    #pragma unroll
    for (int rf = 0; rf < 2; ++rf)
        #pragma unroll
        for (int i = 0; i < 4; ++i) {
            int row = rg * 32 + rf * 16 + q * 4 + i;
            bv_s[row * 33 + cg * 16 + ln] = bestv[rf * 4 + i];
            bk_s[row * 33 + cg * 16 + ln] = bestk[rf * 4 + i];
        }
    __syncthreads();
    if (tid < 64) {
        const float* pv = bv_s + tid * 33;
        const int*   pk = bk_s + tid * 33;
        float bv = pv[0]; int bk = pk[0];
        #pragma unroll
        for (int t = 1; t < 32; ++t) {
            float v = pv[t]; int kk = pk[t];
            if (v > bv || (v == bv && kk < bk)) { bv = v; bk = kk; }
        }
        idx_s[tid] = bk;
        // commitment loss row term: ||z-e*||^2 = ||z||^2 - 2*bestscore
        float lsum = zsq_s[tid] - 2.f * bv;
        #pragma unroll
        for (int off = 32; off; off >>= 1) lsum += __shfl_down(lsum, off);
        if (tid == 0) atomicAdd(out + ND, lsum * (1.0f / (float)ND));
    }
    __syncthreads();

    // ---- epilogue: pure float4 gather + store (no z re-read) ---------------
    #pragma unroll
    for (int i = 0; i < 16; ++i) {
        int item = tid + i * 256;
        int row = item >> 6, c4 = item & 63;
        int k = idx_s[row];
        f32x4 v = *(const f32x4*)(cb + (size_t)k * DDIM + c4 * 4);
        *(f32x4*)(out + (size_t)(b0 + row) * DDIM + c4 * 4) = v;
    }
}

extern "C" void kernel_launch(void* const* d_in, const int* in_sizes, int n_in,
                              void* d_out, int out_size, void* d_ws, size_t ws_size,
                              hipStream_t stream) {
    const float* z  = (const float*)d_in[0];   // z_e, 65536 x 256 fp32
    const float* cb = (const float*)d_in[1];   // codebook, 1024 x 256 fp32
    float* out = (float*)d_out;                // z_q (16777216) ++ loss (1)

    float* half_esq = (float*)d_ws;                         // 4 KB
    short* cb_frag  = (short*)((char*)d_ws + 4096);         // 512 KB bf16 fragments

    vq_prep_kernel<<<128, 256, 0, stream>>>(cb, cb_frag, half_esq, out + ND);
    vq_main_kernel<<<NTOT / 64, 256, 0, stream>>>(z, cb, cb_frag, half_esq, out);
}

// Round 5
// 156.047 us; speedup vs baseline: 1.1533x; 1.0087x over previous
//
#include <hip/hip_runtime.h>

// Problem constants: N=B*T=65536, D=256, K=1024
#define NTOT 65536
#define DDIM 256
#define KCB  1024
#define ND   16777216   // NTOT * DDIM

typedef __attribute__((ext_vector_type(4))) float f32x4;
typedef __attribute__((ext_vector_type(4))) int   i32x4;
typedef __attribute__((ext_vector_type(2))) long long i64x2;

// ---- fp32 -> fp8 e4m3fn (OCP), 4-at-a-time pack into an int (byte i = x_i) --
#if !__has_builtin(__builtin_amdgcn_cvt_pk_fp8_f32)
__device__ static inline unsigned f32_to_e4m3_1(float f) {
    unsigned u = __float_as_uint(f);
    unsigned s = (u >> 24) & 0x80u;
    unsigned a = u & 0x7fffffffu;
    float x = __uint_as_float(a);
    if (x >= 448.f) return s | 0x7Eu;
    if (x < 0.015625f) {                    // subnormal: multiples of 2^-9
        int m = (int)__builtin_rintf(x * 512.f);   // RNE, 0..8
        return s | (unsigned)m;             // m==8 -> 0x08 == 2^-6 normal, correct
    }
    unsigned r = (a + 0x7FFFFu + ((a >> 20) & 1u)) >> 20;   // RNE to 3 mantissa bits
    int E = (int)(r >> 3) - 127;
    unsigned code = ((unsigned)(E + 7) << 3) | (r & 7u);
    if (code >= 0x7Fu) code = 0x7Eu;
    return s | code;
}
#endif

__device__ static inline int pk4_fp8(float x0, float x1, float x2, float x3) {
#if __has_builtin(__builtin_amdgcn_cvt_pk_fp8_f32)
    int w = __builtin_amdgcn_cvt_pk_fp8_f32(x0, x1, 0, false);   // bytes 0,1
    w = __builtin_amdgcn_cvt_pk_fp8_f32(x2, x3, w, true);        // bytes 2,3
    return w;
#else
    return (int)(f32_to_e4m3_1(x0) | (f32_to_e4m3_1(x1) << 8) |
                 (f32_to_e4m3_1(x2) << 16) | (f32_to_e4m3_1(x3) << 24));
#endif
}

// ---------------- Prep: codebook -> fp8(x512) fragments + 256*||e||^2 --------
// Thread -> (code c = gid>>5, j8 = gid&31, d = j8*8). Fragment byte layout:
// frag (chunk cc = c>>4, ks = d>>5) holds lane (q*16 + c&15) bytes for
// k = ks*32 + q*8 + j. Pairs of ks share a 16B slot so the main kernel loads
// 2 frags per dwordx4: addr = ((cc*4 + ks/2)*64 + lane)*16 + (ks&1)*8.
__global__ __launch_bounds__(256) void vq_prep_kernel(const float* __restrict__ cb,
                                                      char* __restrict__ cbf,
                                                      float* __restrict__ esq_scaled,
                                                      float* __restrict__ loss_out) {
    int gid = blockIdx.x * 256 + threadIdx.x;   // 0..32767
    int c = gid >> 5;
    int j8 = gid & 31;
    const float* p = cb + (size_t)c * DDIM + j8 * 8;
    f32x4 x = *(const f32x4*)p;
    f32x4 y = *(const f32x4*)(p + 4);
    float ss = x[0]*x[0] + x[1]*x[1] + x[2]*x[2] + x[3]*x[3]
             + y[0]*y[0] + y[1]*y[1] + y[2]*y[2] + y[3]*y[3];
    #pragma unroll
    for (int m = 16; m; m >>= 1) ss += __shfl_xor(ss, m);   // reduce the 32 lanes of code c
    if (j8 == 0) esq_scaled[c] = 256.f * ss;                // 512 * 0.5 * ||e||^2
    // store fp8(512*e): entries in +-0.5, well inside e4m3 normal range
    int w0 = pk4_fp8(512.f * x[0], 512.f * x[1], 512.f * x[2], 512.f * x[3]);
    int w1 = pk4_fp8(512.f * y[0], 512.f * y[1], 512.f * y[2], 512.f * y[3]);
    int ks = j8 >> 2, qq = j8 & 3;
    int cc = c >> 4, kp = ks >> 1, h = ks & 1;
    int lane2 = qq * 16 + (c & 15);
    size_t addr = ((size_t)(cc * 4 + kp) * 64 + lane2) * 16 + h * 8;
    *(long long*)(cbf + addr) = (long long)(unsigned)w0 | ((long long)w1 << 32);
    if (gid == 0) loss_out[0] = 0.f;
}

// ---------------- Main: barrier-free fp8-MFMA K-loop + argmin + gather -------
// 1024 blocks x 256 thr (4 waves, rg x cg = 2x2). Wave owns 32 rows x 512 cols.
// A-frags fp8 in regs (a[2][8] = 32 VGPR). B-frags stream global->VGPR from the
// 256 KB L2-resident cbf, 1-chunk software pipeline, ZERO barriers in the loop.
// Loss analytic: ||z-e*||^2 = ||z||^2 - 2*best/512.
__global__ __launch_bounds__(256, 3) void vq_main_kernel(const float* __restrict__ z,
                                                         const float* __restrict__ cb,
                                                         const char* __restrict__ cbf,
                                                         const float* __restrict__ esq_scaled,
                                                         float* __restrict__ out) {
    __shared__ float esq_s[KCB];     // 4 KB (scaled: 256*||e||^2)
    __shared__ float zsq_s[64];
    __shared__ float bv_s[64 * 33];  // stride 33: conflict-free reduce rows
    __shared__ int   bk_s[64 * 33];
    __shared__ int   idx_s[64];

    const int tid  = threadIdx.x;
    const int w    = tid >> 6;
    const int lane = tid & 63;
    const int rg   = w >> 1;        // rows rg*32 .. rg*32+31
    const int cg   = w & 1;         // cols cg*512 .. cg*512+511
    const int q    = lane >> 4;
    const int ln   = lane & 15;
    const int b0   = blockIdx.x * 64;

    #pragma unroll
    for (int i = 0; i < 4; ++i) esq_s[tid + i * 256] = esq_scaled[tid + i * 256];

    // ---- A fragments (fp8) + exact fp32 ||z_row||^2 ------------------------
    // A layout: m = lane&15, k = (lane>>4)*8 + j  (j = byte index in the i64).
    long long a[2][8];
    #pragma unroll
    for (int rf = 0; rf < 2; ++rf) {
        float zq = 0.f;
        const float* ap0 = z + (size_t)(b0 + rg * 32 + rf * 16 + ln) * DDIM + q * 8;
        #pragma unroll
        for (int ks = 0; ks < 8; ++ks) {
            f32x4 x = *(const f32x4*)(ap0 + ks * 32);
            f32x4 y = *(const f32x4*)(ap0 + ks * 32 + 4);
            zq += x[0]*x[0] + x[1]*x[1] + x[2]*x[2] + x[3]*x[3]
                + y[0]*y[0] + y[1]*y[1] + y[2]*y[2] + y[3]*y[3];
            int w0 = pk4_fp8(x[0], x[1], x[2], x[3]);
            int w1 = pk4_fp8(y[0], y[1], y[2], y[3]);
            a[rf][ks] = (long long)(unsigned)w0 | ((long long)w1 << 32);
        }
        zq += __shfl_xor(zq, 16);
        zq += __shfl_xor(zq, 32);          // full row sum in every lane
        if (cg == 0 && q == 0) zsq_s[rg * 32 + rf * 16 + ln] = zq;
    }
    __syncthreads();   // esq_s ready (only pre-reduce barrier)

    // ---- K-loop: 32 chunks of 16 cols, software-pipelined, no barriers -----
    float bestv[8];
    int   bestk[8];
    #pragma unroll
    for (int i = 0; i < 8; ++i) { bestv[i] = -1e30f; bestk[i] = 0; }

    const char* bbase = cbf + (size_t)cg * 131072 + lane * 16;   // cg*32 chunks * 4 kp * 1024 B

    i32x4 Bc[4], Bn[4];
    #pragma unroll
    for (int kp = 0; kp < 4; ++kp)
        Bc[kp] = *(const i32x4*)(bbase + (size_t)kp * 1024);

    for (int c = 0; c < 32; ++c) {
        const int cn = (c + 1) & 31;   // wraps to 0 on last iter (harmless re-read)
        #pragma unroll
        for (int kp = 0; kp < 4; ++kp)
            Bn[kp] = *(const i32x4*)(bbase + ((size_t)cn * 4 + kp) * 1024);

        f32x4 acc0 = (f32x4){0.f, 0.f, 0.f, 0.f};
        f32x4 acc1 = (f32x4){0.f, 0.f, 0.f, 0.f};
        #pragma unroll
        for (int kp = 0; kp < 4; ++kp) {
            i64x2 pr = __builtin_bit_cast(i64x2, Bc[kp]);
            acc0 = __builtin_amdgcn_mfma_f32_16x16x32_fp8_fp8(a[0][2 * kp],     pr[0], acc0, 0, 0, 0);
            acc1 = __builtin_amdgcn_mfma_f32_16x16x32_fp8_fp8(a[1][2 * kp],     pr[0], acc1, 0, 0, 0);
            acc0 = __builtin_amdgcn_mfma_f32_16x16x32_fp8_fp8(a[0][2 * kp + 1], pr[1], acc0, 0, 0, 0);
            acc1 = __builtin_amdgcn_mfma_f32_16x16x32_fp8_fp8(a[1][2 * kp + 1], pr[1], acc1, 0, 0, 0);
        }

        // score_scaled = 512*(z.e) - 256*||e||^2 ; C/D: col=lane&15, row=q*4+i.
        // cols ascend with c per lane -> strict '>' keeps lowest index.
        const int col = (cg * 32 + c) * 16 + ln;
        const float e = esq_s[col];
        #pragma unroll
        for (int i = 0; i < 4; ++i) {
            float s0 = acc0[i] - e;
            if (s0 > bestv[i])     { bestv[i]     = s0; bestk[i]     = col; }
            float s1 = acc1[i] - e;
            if (s1 > bestv[4 + i]) { bestv[4 + i] = s1; bestk[4 + i] = col; }
        }
        #pragma unroll
        for (int kp = 0; kp < 4; ++kp) Bc[kp] = Bn[kp];
    }

    // ---- block argmin reduce: 32 candidates per row (2 cg x 16 lanes) ------
    #pragma unroll
    for (int rf = 0; rf < 2; ++rf)
        #pragma unroll
        for (int i = 0; i < 4; ++i) {
            int row = rg * 32 + rf * 16 + q * 4 + i;
            bv_s[row * 33 + cg * 16 + ln] = bestv[rf * 4 + i];
            bk_s[row * 33 + cg * 16 + ln] = bestk[rf * 4 + i];
        }
    __syncthreads();
    if (tid < 64) {
        const float* pv = bv_s + tid * 33;
        const int*   pk = bk_s + tid * 33;
        float bv = pv[0]; int bk = pk[0];
        #pragma unroll
        for (int t = 1; t < 32; ++t) {
            float v = pv[t]; int kk = pk[t];
            if (v > bv || (v == bv && kk < bk)) { bv = v; bk = kk; }
        }
        idx_s[tid] = bk;
        // row loss: ||z-e*||^2 = ||z||^2 - 2*(best_scaled/512)
        float lsum = zsq_s[tid] - bv * 0.00390625f;
        #pragma unroll
        for (int off = 32; off; off >>= 1) lsum += __shfl_down(lsum, off);
        if (tid == 0) atomicAdd(out + ND, lsum * (1.0f / (float)ND));
    }
    __syncthreads();

    // ---- epilogue: pure float4 gather + store (no z re-read) ---------------
    #pragma unroll
    for (int i = 0; i < 16; ++i) {
        int item = tid + i * 256;
        int row = item >> 6, c4 = item & 63;
        int k = idx_s[row];
        f32x4 v = *(const f32x4*)(cb + (size_t)k * DDIM + c4 * 4);
        *(f32x4*)(out + (size_t)(b0 + row) * DDIM + c4 * 4) = v;
    }
}

extern "C" void kernel_launch(void* const* d_in, const int* in_sizes, int n_in,
                              void* d_out, int out_size, void* d_ws, size_t ws_size,
                              hipStream_t stream) {
    const float* z  = (const float*)d_in[0];   // z_e, 65536 x 256 fp32
    const float* cb = (const float*)d_in[1];   // codebook, 1024 x 256 fp32
    float* out = (float*)d_out;                // z_q (16777216) ++ loss (1)

    float* esq_scaled = (float*)d_ws;                    // 4 KB
    char*  cb_frag    = (char*)d_ws + 4096;              // 256 KB fp8 fragments

    vq_prep_kernel<<<128, 256, 0, stream>>>(cb, cb_frag, esq_scaled, out + ND);
    vq_main_kernel<<<NTOT / 64, 256, 0, stream>>>(z, cb, cb_frag, esq_scaled, out);
}